// Round 8
// baseline (190.445 us; speedup 1.0000x reference)
//
#include <hip/hip_runtime.h>
#include <cmath>

#define TAPE_SZ 100000
#define N_SZ    50000
#define F_SZ    32
#define B_SZ    128
#define NCHUNK  8       // b-chunks (one per XCD under %8 round-robin)
#define CB      16      // b's per chunk; chunk = TAPE_SZ*CB*2B = 3.2 MB < 4 MB L2
#define NB      128     // n's per gather block

// Manual round-to-nearest-even f32 -> bf16 bits (no __hip_bfloat16 API deps).
static __device__ __forceinline__ unsigned short f32_to_bf16(float f) {
    unsigned int u = __float_as_uint(f);
    u = (u + 0x7fffu + ((u >> 16) & 1u)) >> 16;
    return (unsigned short)u;
}

// ---------------------------------------------------------------------------
// Kernel A: tape (B x TAPE f32) -> tapeT chunked [NCHUNK][TAPE][CB] bf16,
// float4 global loads, 16B chunk-contiguous stores, fused tail copy.
// ---------------------------------------------------------------------------
__global__ __launch_bounds__(256) void transpose_tape(const float* __restrict__ in,
                                                      unsigned short* __restrict__ outT,
                                                      float* __restrict__ out) {
    __shared__ float tile[32 * 133];
    const int x0  = blockIdx.x * 32;
    const int tid = threadIdx.x;
    {
        const int xq = tid & 7;
        const int b0 = tid >> 3;
        const bool tail = (x0 + xq * 4 >= N_SZ);   // 50000 % 4 == 0
        #pragma unroll
        for (int it = 0; it < 4; ++it) {
            const int b = b0 + it * 32;
            const float4 v = *(const float4*)(in + (size_t)b * TAPE_SZ + x0 + xq * 4);
            tile[(xq * 4 + 0) * 133 + b] = v.x;
            tile[(xq * 4 + 1) * 133 + b] = v.y;
            tile[(xq * 4 + 2) * 133 + b] = v.z;
            tile[(xq * 4 + 3) * 133 + b] = v.w;
            if (tail) *(float4*)(out + (size_t)b * TAPE_SZ + x0 + xq * 4) = v;
        }
    }
    __syncthreads();
    {
        const int s  = tid & 63;
        const int w  = tid >> 6;
        const int h  = s & 1;
        const int xr = s >> 1;
        #pragma unroll
        for (int j = 0; j < 2; ++j) {
            const int c = w + 4 * j;
            const float* src = &tile[xr * 133 + c * CB + h * 8];
            union { unsigned short u[8]; uint4 q; } pk;
            #pragma unroll
            for (int k = 0; k < 8; ++k) pk.u[k] = f32_to_bf16(src[k]);
            *(uint4*)(outT + ((size_t)c * TAPE_SZ + x0 + xr) * CB + h * 8) = pk.q;
        }
    }
}

// ---------------------------------------------------------------------------
// Kernel B: gather-matmul from chunked bf16 tapeT.
// Block 256 = 2 b-octets x 128 n; chunk = blockIdx & 7 (XCD L2 affinity).
// Depth-32 register pipeline: issue ALL 32 gathers (uint4 q[32], 128 VGPR)
// before the FMA sweep -> ~384 outstanding loads/CU at 12 waves/CU.
// ---------------------------------------------------------------------------
__global__ __launch_bounds__(256, 3) void gather_mm(const unsigned short* __restrict__ tapeT,
                                                    const float* __restrict__ weights,
                                                    const float* __restrict__ bias,
                                                    const int*   __restrict__ in_idx,
                                                    const int*   __restrict__ out_idx,
                                                    const int*   __restrict__ act_type,
                                                    float* __restrict__ out) {
    __shared__ int   s_idx[NB][33];   // pitch 33 -> conflict-free (bank=(nl+f)%32)
    __shared__ float s_w[NB][33];
    __shared__ float s_bias[NB];
    __shared__ int   s_act[NB];
    __shared__ int   s_oidx[NB];

    const int tid  = threadIdx.x;
    const int c    = blockIdx.x & 7;
    const int n0   = (blockIdx.x >> 3) * NB;
    const int nmax = (N_SZ - n0 < NB) ? (N_SZ - n0) : NB;

    const uint4*  gi = (const uint4*)(in_idx)   + (size_t)n0 * 8;
    const float4* gw = (const float4*)(weights) + (size_t)n0 * 8;
    for (int i = tid; i < nmax * 8; i += 256) {
        const int n  = i >> 3;
        const int f0 = (i & 7) * 4;
        const uint4  vi = gi[i];
        const float4 vw = gw[i];
        s_idx[n][f0 + 0] = vi.x;
        s_idx[n][f0 + 1] = vi.y;
        s_idx[n][f0 + 2] = vi.z;
        s_idx[n][f0 + 3] = vi.w;
        s_w[n][f0 + 0] = vw.x;
        s_w[n][f0 + 1] = vw.y;
        s_w[n][f0 + 2] = vw.z;
        s_w[n][f0 + 3] = vw.w;
    }
    if (tid < nmax) {
        s_bias[tid] = bias[n0 + tid];
        s_act[tid]  = act_type[n0 + tid];
        s_oidx[tid] = out_idx[n0 + tid];
    }
    __syncthreads();

    const int oct = tid & 1;
    const int nl  = tid >> 1;
    if (nl < nmax) {
        const unsigned short* base = tapeT + (size_t)c * TAPE_SZ * CB + oct * 8;

        // Phase 1: issue all 32 independent gathers.
        uint4 q[32];
        #pragma unroll
        for (int f = 0; f < 32; ++f)
            q[f] = *(const uint4*)(base + (size_t)s_idx[nl][f] * CB);

        // Phase 2: FMA sweep (compiler interleaves with descending vmcnt).
        float a0 = 0.f, a1 = 0.f, a2 = 0.f, a3 = 0.f, a4 = 0.f, a5 = 0.f, a6 = 0.f, a7 = 0.f;
        #pragma unroll
        for (int f = 0; f < 32; ++f) {
            const float w = s_w[nl][f];
            a0 = fmaf(__uint_as_float(q[f].x << 16),         w, a0);
            a1 = fmaf(__uint_as_float(q[f].x & 0xffff0000u), w, a1);
            a2 = fmaf(__uint_as_float(q[f].y << 16),         w, a2);
            a3 = fmaf(__uint_as_float(q[f].y & 0xffff0000u), w, a3);
            a4 = fmaf(__uint_as_float(q[f].z << 16),         w, a4);
            a5 = fmaf(__uint_as_float(q[f].z & 0xffff0000u), w, a5);
            a6 = fmaf(__uint_as_float(q[f].w << 16),         w, a6);
            a7 = fmaf(__uint_as_float(q[f].w & 0xffff0000u), w, a7);
        }

        const float bz = s_bias[nl];
        a0 += bz; a1 += bz; a2 += bz; a3 += bz; a4 += bz; a5 += bz; a6 += bz; a7 += bz;
        if (s_act[nl] == 0) {
            a0 = fmaxf(a0, 0.f); a1 = fmaxf(a1, 0.f); a2 = fmaxf(a2, 0.f); a3 = fmaxf(a3, 0.f);
            a4 = fmaxf(a4, 0.f); a5 = fmaxf(a5, 0.f); a6 = fmaxf(a6, 0.f); a7 = fmaxf(a7, 0.f);
        } else {
            a0 = tanhf(a0); a1 = tanhf(a1); a2 = tanhf(a2); a3 = tanhf(a3);
            a4 = tanhf(a4); a5 = tanhf(a5); a6 = tanhf(a6); a7 = tanhf(a7);
        }
        const int oc = s_oidx[nl];
        const int bb = c * CB + oct * 8;
        out[(size_t)(bb + 0) * TAPE_SZ + oc] = a0;
        out[(size_t)(bb + 1) * TAPE_SZ + oc] = a1;
        out[(size_t)(bb + 2) * TAPE_SZ + oc] = a2;
        out[(size_t)(bb + 3) * TAPE_SZ + oc] = a3;
        out[(size_t)(bb + 4) * TAPE_SZ + oc] = a4;
        out[(size_t)(bb + 5) * TAPE_SZ + oc] = a5;
        out[(size_t)(bb + 6) * TAPE_SZ + oc] = a6;
        out[(size_t)(bb + 7) * TAPE_SZ + oc] = a7;
    }
}

// ---------------------------------------------------------------------------
// Fallback (workspace too small): direct uncoalesced gather. Correct, slow.
// ---------------------------------------------------------------------------
__global__ __launch_bounds__(128) void gather_fallback(const float* __restrict__ tape,
                                                       const float* __restrict__ weights,
                                                       const float* __restrict__ bias,
                                                       const int*   __restrict__ in_idx,
                                                       const int*   __restrict__ out_idx,
                                                       const int*   __restrict__ act_type,
                                                       float* __restrict__ out) {
    const int n = blockIdx.x;
    const int b = threadIdx.x;
    float acc = 0.f;
    for (int f = 0; f < F_SZ; ++f) {
        acc += tape[(size_t)b * TAPE_SZ + in_idx[(size_t)n * F_SZ + f]] *
               weights[(size_t)n * F_SZ + f];
    }
    acc += bias[n];
    acc = (act_type[n] == 0) ? fmaxf(acc, 0.f) : tanhf(acc);
    out[(size_t)b * TAPE_SZ + out_idx[n]] = acc;
}

__global__ __launch_bounds__(256) void copy_tail_fb(const float* __restrict__ tape,
                                                    float* __restrict__ out) {
    const int n4 = (TAPE_SZ - N_SZ) / 4;
    int i = blockIdx.x * blockDim.x + threadIdx.x;
    int b = blockIdx.y;
    if (i < n4) {
        const float4* src = (const float4*)(tape + (size_t)b * TAPE_SZ + N_SZ);
        float4*       dst = (float4*)(out  + (size_t)b * TAPE_SZ + N_SZ);
        dst[i] = src[i];
    }
}

extern "C" void kernel_launch(void* const* d_in, const int* in_sizes, int n_in,
                              void* d_out, int out_size, void* d_ws, size_t ws_size,
                              hipStream_t stream) {
    const float* tape    = (const float*)d_in[0];
    const float* weights = (const float*)d_in[1];
    const float* bias    = (const float*)d_in[2];
    const int*   in_idx  = (const int*)d_in[3];
    const int*   out_idx = (const int*)d_in[4];
    const int*   act     = (const int*)d_in[5];
    float*       out     = (float*)d_out;

    const size_t need = (size_t)NCHUNK * TAPE_SZ * CB * sizeof(unsigned short);
    if (ws_size >= need) {
        unsigned short* tapeT = (unsigned short*)d_ws;
        transpose_tape<<<dim3(TAPE_SZ / 32), dim3(256), 0, stream>>>(tape, tapeT, out);
        const int ntiles = (N_SZ + NB - 1) / NB;   // 391
        gather_mm<<<dim3(ntiles * NCHUNK), dim3(256), 0, stream>>>(
            tapeT, weights, bias, in_idx, out_idx, act, out);
    } else {
        copy_tail_fb<<<dim3(((TAPE_SZ - N_SZ) / 4 + 255) / 256, B_SZ), 256, 0, stream>>>(tape, out);
        gather_fallback<<<dim3(N_SZ), 128, 0, stream>>>(
            tape, weights, bias, in_idx, out_idx, act, out);
    }
}

// Round 11
// 170.623 us; speedup vs baseline: 1.1162x; 1.1162x over previous
//
#include <hip/hip_runtime.h>
#include <cmath>

#define TAPE_SZ 100000
#define N_SZ    50000
#define F_SZ    32
#define B_SZ    128
#define NB      16      // n's per gather block (50000/16 = 3125 exact)
#define NGATHER 3125
#define NTAIL   512
#define TAIL_F4 1600000 // 128 b * 12500 float4 tail elements

// Manual round-to-nearest-even f32 -> bf16 bits.
static __device__ __forceinline__ unsigned short f32_to_bf16(float f) {
    unsigned int u = __float_as_uint(f);
    u = (u + 0x7fffu + ((u >> 16) & 1u)) >> 16;
    return (unsigned short)u;
}

// ---------------------------------------------------------------------------
// Kernel A: transpose tape (B x TAPE fp32) -> tapeT (TAPE x B bf16), 16B
// packed stores. Tail copy moved to the gather kernel (overlaps TCP slack).
// ---------------------------------------------------------------------------
__global__ __launch_bounds__(256) void transpose_tape(const float* __restrict__ in,
                                                      unsigned short* __restrict__ outT) {
    __shared__ float tile[32][129];
    const int x0 = blockIdx.x * 32;
    const int tx = threadIdx.x;       // x_local 0..31
    const int ty = threadIdx.y;       // 0..7

    #pragma unroll
    for (int yy = ty; yy < B_SZ; yy += 8)
        tile[tx][yy] = in[(size_t)yy * TAPE_SZ + x0 + tx];
    __syncthreads();

    const int tid = ty * 32 + tx;
    const int oct = tid & 15;         // b-octet (8 bf16 = 16B)
    const int xl0 = tid >> 4;         // 0..15
    #pragma unroll
    for (int xx = xl0; xx < 32; xx += 16) {
        const float* src = &tile[xx][oct * 8];
        union { unsigned short u[8]; uint4 q; } pk;
        #pragma unroll
        for (int k = 0; k < 8; ++k)
            pk.u[k] = f32_to_bf16(src[k]);
        *(uint4*)(outT + (size_t)(x0 + xx) * B_SZ + oct * 8) = pk.q;
    }
}

// ---------------------------------------------------------------------------
// Kernel B: gather-matmul (blocks 0..NGATHER-1) + tail copy (rest).
// Gather: R6 proven core; epilogue now uses float4 stores over 4 consecutive
// output columns (cuts store lane-requests 4x; scalar fallback if the
// output_indices quad isn't consecutive/aligned).
// ---------------------------------------------------------------------------
__global__ __launch_bounds__(256) void gather_mm(const unsigned short* __restrict__ tapeT,
                                                 const float* __restrict__ weights,
                                                 const float* __restrict__ bias,
                                                 const int*   __restrict__ in_idx,
                                                 const int*   __restrict__ out_idx,
                                                 const int*   __restrict__ act_type,
                                                 const float* __restrict__ tape,
                                                 float* __restrict__ out) {
    __shared__ int   s_idx[NB][33];   // pitch 33: conflict-free broadcast reads
    __shared__ float s_w[NB][33];
    __shared__ float s_bias[NB];
    __shared__ int   s_act[NB];
    __shared__ int   s_oidx[NB];
    __shared__ float s_x[NB][132];    // [n_local][b]

    const int tid = threadIdx.x;

    if (blockIdx.x >= NGATHER) {
        // ---- tail copy: columns [N_SZ, TAPE_SZ) survive into out ----
        const float4* src = (const float4*)tape;
        float4*       dst = (float4*)out;
        const int stride = NTAIL * 256;
        for (int i = (blockIdx.x - NGATHER) * 256 + tid; i < TAIL_F4; i += stride) {
            const int b = i / 12500;              // const div -> magic mul
            const int j = i - b * 12500;
            const int off = b * (TAPE_SZ / 4) + (N_SZ / 4) + j;
            dst[off] = src[off];
        }
        return;
    }

    const int n0 = blockIdx.x * NB;

    #pragma unroll
    for (int t = tid; t < NB * 32; t += 256) {
        const int n = t >> 5, f = t & 31;
        s_idx[n][f] = in_idx[(size_t)n0 * 32 + t];
        s_w[n][f]   = weights[(size_t)n0 * 32 + t];
    }
    if (tid < NB) {
        s_bias[tid] = bias[n0 + tid];
        s_act[tid]  = act_type[n0 + tid];
        s_oidx[tid] = out_idx[n0 + tid];
    }
    __syncthreads();

    const int nl = tid >> 4;              // n_local 0..15
    const int bx = tid & 15;              // b-octet: b = 8*bx .. 8*bx+7
    float a0 = 0.f, a1 = 0.f, a2 = 0.f, a3 = 0.f, a4 = 0.f, a5 = 0.f, a6 = 0.f, a7 = 0.f;

    #pragma unroll
    for (int fo = 0; fo < 32; fo += 8) {
        int   i8[8]; float w8[8];
        #pragma unroll
        for (int j = 0; j < 8; ++j) { i8[j] = s_idx[nl][fo + j]; w8[j] = s_w[nl][fo + j]; }
        uint4 q8[8];
        #pragma unroll
        for (int j = 0; j < 8; ++j)
            q8[j] = *(const uint4*)(tapeT + (size_t)i8[j] * B_SZ + bx * 8);
        #pragma unroll
        for (int j = 0; j < 8; ++j) {
            const float w = w8[j];
            a0 = fmaf(__uint_as_float(q8[j].x << 16),         w, a0);
            a1 = fmaf(__uint_as_float(q8[j].x & 0xffff0000u), w, a1);
            a2 = fmaf(__uint_as_float(q8[j].y << 16),         w, a2);
            a3 = fmaf(__uint_as_float(q8[j].y & 0xffff0000u), w, a3);
            a4 = fmaf(__uint_as_float(q8[j].z << 16),         w, a4);
            a5 = fmaf(__uint_as_float(q8[j].z & 0xffff0000u), w, a5);
            a6 = fmaf(__uint_as_float(q8[j].w << 16),         w, a6);
            a7 = fmaf(__uint_as_float(q8[j].w & 0xffff0000u), w, a7);
        }
    }

    const float bz = s_bias[nl];
    a0 += bz; a1 += bz; a2 += bz; a3 += bz; a4 += bz; a5 += bz; a6 += bz; a7 += bz;
    if (s_act[nl] == 0) {
        a0 = fmaxf(a0, 0.f); a1 = fmaxf(a1, 0.f); a2 = fmaxf(a2, 0.f); a3 = fmaxf(a3, 0.f);
        a4 = fmaxf(a4, 0.f); a5 = fmaxf(a5, 0.f); a6 = fmaxf(a6, 0.f); a7 = fmaxf(a7, 0.f);
    } else {
        a0 = tanhf(a0); a1 = tanhf(a1); a2 = tanhf(a2); a3 = tanhf(a3);
        a4 = tanhf(a4); a5 = tanhf(a5); a6 = tanhf(a6); a7 = tanhf(a7);
    }
    {
        const int b8 = bx * 8;
        s_x[nl][b8 + 0] = a0; s_x[nl][b8 + 1] = a1; s_x[nl][b8 + 2] = a2; s_x[nl][b8 + 3] = a3;
        s_x[nl][b8 + 4] = a4; s_x[nl][b8 + 5] = a5; s_x[nl][b8 + 6] = a6; s_x[nl][b8 + 7] = a7;
    }
    __syncthreads();

    // Epilogue: wave w owns n-quad g=w; lanes sweep b. float4 store over 4
    // consecutive output columns when possible (4x fewer store lane-requests).
    const int g  = tid >> 6;              // n-quad 0..3
    const int b0 = tid & 63;              // b
    const int oc0 = s_oidx[g * 4];
    const bool consec = (s_oidx[g * 4 + 1] == oc0 + 1) &&
                        (s_oidx[g * 4 + 2] == oc0 + 2) &&
                        (s_oidx[g * 4 + 3] == oc0 + 3) && ((oc0 & 3) == 0);
    #pragma unroll
    for (int rep = 0; rep < 2; ++rep) {
        const int b = b0 + rep * 64;
        const float4 v = make_float4(s_x[g * 4 + 0][b], s_x[g * 4 + 1][b],
                                     s_x[g * 4 + 2][b], s_x[g * 4 + 3][b]);
        if (consec) {
            *(float4*)(out + (size_t)b * TAPE_SZ + oc0) = v;
        } else {
            out[(size_t)b * TAPE_SZ + s_oidx[g * 4 + 0]] = v.x;
            out[(size_t)b * TAPE_SZ + s_oidx[g * 4 + 1]] = v.y;
            out[(size_t)b * TAPE_SZ + s_oidx[g * 4 + 2]] = v.z;
            out[(size_t)b * TAPE_SZ + s_oidx[g * 4 + 3]] = v.w;
        }
    }
}

// ---------------------------------------------------------------------------
// Fallback (workspace too small): direct uncoalesced gather. Correct, slow.
// ---------------------------------------------------------------------------
__global__ __launch_bounds__(128) void gather_fallback(const float* __restrict__ tape,
                                                       const float* __restrict__ weights,
                                                       const float* __restrict__ bias,
                                                       const int*   __restrict__ in_idx,
                                                       const int*   __restrict__ out_idx,
                                                       const int*   __restrict__ act_type,
                                                       float* __restrict__ out) {
    const int n = blockIdx.x;
    const int b = threadIdx.x;
    float acc = 0.f;
    for (int f = 0; f < F_SZ; ++f) {
        acc += tape[(size_t)b * TAPE_SZ + in_idx[(size_t)n * F_SZ + f]] *
               weights[(size_t)n * F_SZ + f];
    }
    acc += bias[n];
    acc = (act_type[n] == 0) ? fmaxf(acc, 0.f) : tanhf(acc);
    out[(size_t)b * TAPE_SZ + out_idx[n]] = acc;
}

__global__ __launch_bounds__(256) void copy_tail_fb(const float* __restrict__ tape,
                                                    float* __restrict__ out) {
    const int n4 = (TAPE_SZ - N_SZ) / 4;
    int i = blockIdx.x * blockDim.x + threadIdx.x;
    int b = blockIdx.y;
    if (i < n4) {
        const float4* src = (const float4*)(tape + (size_t)b * TAPE_SZ + N_SZ);
        float4*       dst = (float4*)(out  + (size_t)b * TAPE_SZ + N_SZ);
        dst[i] = src[i];
    }
}

extern "C" void kernel_launch(void* const* d_in, const int* in_sizes, int n_in,
                              void* d_out, int out_size, void* d_ws, size_t ws_size,
                              hipStream_t stream) {
    const float* tape    = (const float*)d_in[0];
    const float* weights = (const float*)d_in[1];
    const float* bias    = (const float*)d_in[2];
    const int*   in_idx  = (const int*)d_in[3];
    const int*   out_idx = (const int*)d_in[4];
    const int*   act     = (const int*)d_in[5];
    float*       out     = (float*)d_out;

    const size_t need = (size_t)TAPE_SZ * B_SZ * sizeof(unsigned short);
    if (ws_size >= need) {
        unsigned short* tapeT = (unsigned short*)d_ws;
        transpose_tape<<<dim3(TAPE_SZ / 32), dim3(32, 8), 0, stream>>>(tape, tapeT);
        gather_mm<<<dim3(NGATHER + NTAIL), dim3(256), 0, stream>>>(
            tapeT, weights, bias, in_idx, out_idx, act, tape, out);
    } else {
        copy_tail_fb<<<dim3(((TAPE_SZ - N_SZ) / 4 + 255) / 256, B_SZ), 256, 0, stream>>>(tape, out);
        gather_fallback<<<dim3(N_SZ), 128, 0, stream>>>(
            tape, weights, bias, in_idx, out_idx, act, out);
    }
}